// Round 1
// baseline (950.583 us; speedup 1.0000x reference)
//
#include <hip/hip_runtime.h>
#include <math.h>

#define NROWS 16384
#define DIM 256
#define MC 1024
#define BK 64

constexpr float kDecay = 0.99f;
constexpr float kEps = 1e-5f;
constexpr float kTemp = 0.1f;
constexpr float kCommit = 0.25f;
constexpr float kMaxEnt = 6.93147180559945f; // ln(1024)

__device__ __forceinline__ float wave_sum(float v) {
#pragma unroll
  for (int off = 32; off > 0; off >>= 1) v += __shfl_xor(v, off);
  return v;
}
__device__ __forceinline__ float wave_max(float v) {
#pragma unroll
  for (int off = 32; off > 0; off >>= 1) v = fmaxf(v, __shfl_xor(v, off));
  return v;
}

// C[r][c] = sum_k X[r][k] * W[c][k]   (both row-major, K=DIM=256)
// grid: (MC/64, nrows/64), block 256. 64x64 tile, each thread 4x4.
__global__ __launch_bounds__(256) void gemm_nt(const float* __restrict__ X,
                                               const float* __restrict__ W,
                                               float* __restrict__ C) {
  __shared__ float As[BK][68];  // k-major, pad 4 floats -> 16B-aligned rows
  __shared__ float Bs[BK][68];
  const int tid = threadIdx.x;
  const int row0 = blockIdx.y * 64;
  const int col0 = blockIdx.x * 64;
  const int lr = tid >> 4;         // 0..15
  const int lk = (tid & 15) << 2;  // 0..60
  const int tr = tid >> 4;         // 0..15 -> rows tr*4..+3
  const int tc = tid & 15;         // cols tc*4..+3
  float acc[4][4] = {{0.f, 0.f, 0.f, 0.f}};
  for (int k0 = 0; k0 < DIM; k0 += BK) {
#pragma unroll
    for (int i = 0; i < 4; ++i) {
      const int r = lr + (i << 4);
      const float4 av = *reinterpret_cast<const float4*>(X + (size_t)(row0 + r) * DIM + k0 + lk);
      As[lk + 0][r] = av.x; As[lk + 1][r] = av.y; As[lk + 2][r] = av.z; As[lk + 3][r] = av.w;
      const float4 bv = *reinterpret_cast<const float4*>(W + (size_t)(col0 + r) * DIM + k0 + lk);
      Bs[lk + 0][r] = bv.x; Bs[lk + 1][r] = bv.y; Bs[lk + 2][r] = bv.z; Bs[lk + 3][r] = bv.w;
    }
    __syncthreads();
#pragma unroll
    for (int k = 0; k < BK; ++k) {
      const float4 a4 = *reinterpret_cast<const float4*>(&As[k][tr << 2]);
      const float4 b4 = *reinterpret_cast<const float4*>(&Bs[k][tc << 2]);
      const float a[4] = {a4.x, a4.y, a4.z, a4.w};
      const float b[4] = {b4.x, b4.y, b4.z, b4.w};
#pragma unroll
      for (int i = 0; i < 4; ++i)
#pragma unroll
        for (int j = 0; j < 4; ++j) acc[i][j] = fmaf(a[i], b[j], acc[i][j]);
    }
    __syncthreads();
  }
#pragma unroll
  for (int i = 0; i < 4; ++i) {
    const float4 o = make_float4(acc[i][0], acc[i][1], acc[i][2], acc[i][3]);
    *reinterpret_cast<float4*>(C + (size_t)(row0 + (tr << 2) + i) * MC + col0 + (tc << 2)) = o;
  }
}

// sum of squares per row of a [nrows, DIM] matrix; one wave per row
__global__ __launch_bounds__(256) void rowsq(const float* __restrict__ X, float* __restrict__ out,
                                             int nrows) {
  const int w = (int)((blockIdx.x * blockDim.x + threadIdx.x) >> 6);
  const int lane = threadIdx.x & 63;
  if (w >= nrows) return;
  const float4 x = *reinterpret_cast<const float4*>(X + (size_t)w * DIM + (lane << 2));
  float s = x.x * x.x + x.y * x.y + x.z * x.z + x.w * x.w;
  s = wave_sum(s);
  if (lane == 0) out[w] = s;
}

// per-row: dist = esq + xsq - 2*dot; argmin (first index on ties),
// entropy of softmax(-sqrt(max(dist,0))) with log(p+1e-5); adj = 1 - H/lnM
__global__ __launch_bounds__(256) void scan_dist(const float* __restrict__ dot,
                                                 const float* __restrict__ esq,
                                                 const float* __restrict__ xsq,
                                                 int* __restrict__ idx_out,
                                                 float* __restrict__ adj_out) {
  const int row = (int)((blockIdx.x * blockDim.x + threadIdx.x) >> 6);
  const int lane = threadIdx.x & 63;
  const float* drow = dot + (size_t)row * MC;
  const float xs = xsq[row];
  float sv[16];
  float bestv = INFINITY;
  int besti = MC;
  float smax = -INFINITY;
#pragma unroll
  for (int j = 0; j < 16; ++j) {
    const int m = lane + (j << 6);
    const float dv = esq[m] + xs - 2.0f * drow[m];
    if (dv < bestv || (dv == bestv && m < besti)) { bestv = dv; besti = m; }
    const float s = -sqrtf(fmaxf(dv, 0.0f));
    sv[j] = s;
    smax = fmaxf(smax, s);
  }
#pragma unroll
  for (int off = 32; off > 0; off >>= 1) {
    const float ov = __shfl_xor(bestv, off);
    const int oi = __shfl_xor(besti, off);
    if (ov < bestv || (ov == bestv && oi < besti)) { bestv = ov; besti = oi; }
    smax = fmaxf(smax, __shfl_xor(smax, off));
  }
  float se = 0.f;
#pragma unroll
  for (int j = 0; j < 16; ++j) se += expf(sv[j] - smax);
  se = wave_sum(se);
  float H = 0.f;
#pragma unroll
  for (int j = 0; j < 16; ++j) {
    const float p = expf(sv[j] - smax) / se;
    H -= p * logf(p + 1e-5f);
  }
  H = wave_sum(H);
  if (lane == 0) {
    idx_out[row] = besti;
    adj_out[row] = 1.0f - H / kMaxEnt;
  }
}

// EMA scatter: one block per row
__global__ __launch_bounds__(256) void scatter_ema(
    const float* __restrict__ a, const float* __restrict__ v, const int* __restrict__ aidx,
    const float* __restrict__ aadj, const int* __restrict__ vidx, const float* __restrict__ vadj,
    float* __restrict__ acc_a, float* __restrict__ acc_v, float* __restrict__ cnt_a,
    float* __restrict__ cnt_v) {
  const int row = blockIdx.x;
  const int d = threadIdx.x;
  const size_t o = (size_t)row * DIM + d;
  const float s = a[o] + v[o];
  const int ia = aidx[row], iv = vidx[row];
  const float wa = aadj[row], wv = vadj[row];
  atomicAdd(acc_a + (size_t)ia * DIM + d, wa * s);
  atomicAdd(acc_v + (size_t)iv * DIM + d, wv * s);
  if (d == 0) {
    atomicAdd(cnt_a + ia, wa);
    atomicAdd(cnt_v + iv, wv);
  }
}

// two-pass EMA count update with Laplace smoothing; single block of 1024
__global__ __launch_bounds__(1024) void ec_kernel(const float* __restrict__ ema_count,
                                                  const float* __restrict__ cnt_v,
                                                  const float* __restrict__ cnt_a,
                                                  float* __restrict__ ec_out) {
  __shared__ float red[1024];
  const int m = threadIdx.x;
  float ec = kDecay * ema_count[m] + (1.f - kDecay) * cnt_v[m];
  red[m] = ec;
  __syncthreads();
  for (int s = 512; s > 0; s >>= 1) {
    if (m < s) red[m] += red[m + s];
    __syncthreads();
  }
  float n = red[0];
  __syncthreads();
  ec = (ec + kEps) / (n + MC * kEps) * n;
  ec = kDecay * ec + (1.f - kDecay) * cnt_a[m];
  red[m] = ec;
  __syncthreads();
  for (int s = 512; s > 0; s >>= 1) {
    if (m < s) red[m] += red[m + s];
    __syncthreads();
  }
  n = red[0];
  ec = (ec + kEps) / (n + MC * kEps) * n;
  ec_out[m] = ec;
}

// emb_new = ew2/ec; en = row-normalized. one block per code
__global__ __launch_bounds__(256) void en_kernel(const float* __restrict__ ema_weight,
                                                 const float* __restrict__ acc_v,
                                                 const float* __restrict__ acc_a,
                                                 const float* __restrict__ ec,
                                                 float* __restrict__ en) {
  const int mcode = blockIdx.x;
  const int d = threadIdx.x;
  const size_t o = (size_t)mcode * DIM + d;
  float ew = kDecay * ema_weight[o] + 0.5f * (1.f - kDecay) * acc_v[o];
  ew = kDecay * ew + 0.5f * (1.f - kDecay) * acc_a[o];
  const float e = ew / ec[mcode];
  __shared__ float red[256];
  red[d] = e * e;
  __syncthreads();
  for (int s = 128; s > 0; s >>= 1) {
    if (d < s) red[d] += red[d + s];
    __syncthreads();
  }
  const float nrm = sqrtf(red[0]);
  en[o] = e / fmaxf(nrm, 1e-8f);
}

// per-row online logsumexp of dot*inv; accumulate (l[self]-lse) and (l[coup]-lse)
__global__ __launch_bounds__(256) void scan_nce(const float* __restrict__ dot,
                                                const float* __restrict__ xsq,
                                                const int* __restrict__ sidx,
                                                const int* __restrict__ cidx,
                                                float* __restrict__ acc2) {
  __shared__ float part[8];
  const int row = (int)((blockIdx.x * blockDim.x + threadIdx.x) >> 6);
  const int lane = threadIdx.x & 63;
  const int wib = threadIdx.x >> 6;
  const float* drow = dot + (size_t)row * MC;
  const float inv = 1.0f / (fmaxf(sqrtf(xsq[row]), 1e-8f) * kTemp);
  float l[16];
  float lmax = -INFINITY;
#pragma unroll
  for (int j = 0; j < 16; ++j) {
    l[j] = drow[lane + (j << 6)] * inv;
    lmax = fmaxf(lmax, l[j]);
  }
  lmax = wave_max(lmax);
  float se = 0.f;
#pragma unroll
  for (int j = 0; j < 16; ++j) se += expf(l[j] - lmax);
  se = wave_sum(se);
  const float lse = lmax + logf(se);
  const int si = sidx[row], ci = cidx[row];
  float st = 0.f, ct = 0.f;
#pragma unroll
  for (int j = 0; j < 16; ++j) {
    const int m = lane + (j << 6);
    if (m == si) st = l[j] - lse;
    if (m == ci) ct = l[j] - lse;
  }
  st = wave_sum(st);
  ct = wave_sum(ct);
  if (lane == 0) {
    part[wib] = st;
    part[4 + wib] = ct;
  }
  __syncthreads();
  if (threadIdx.x == 0) {
    atomicAdd(acc2 + 0, part[0] + part[1] + part[2] + part[3]);
    atomicAdd(acc2 + 1, part[4] + part[5] + part[6] + part[7]);
  }
}

__global__ void finalize(const float* __restrict__ acc4, float* __restrict__ out) {
  const float invN = 1.0f / (float)NROWS;
  const float ce_as = -acc4[0] * invN, ce_ac = -acc4[1] * invN;
  const float ce_vs = -acc4[2] * invN, ce_vc = -acc4[3] * invN;
  const float a_cpcl = kCommit * ce_as + (1.f - kCommit) * ce_ac;
  const float v_cpcl = kCommit * ce_vs + (1.f - kCommit) * ce_vc;
  out[0] = (kCommit * a_cpcl + kCommit * v_cpcl) / 32.0f;
}

extern "C" void kernel_launch(void* const* d_in, const int* in_sizes, int n_in, void* d_out,
                              int out_size, void* d_ws, size_t ws_size, hipStream_t stream) {
  const float* audio = (const float*)d_in[0];
  const float* video = (const float*)d_in[1];
  const float* emb = (const float*)d_in[2];
  const float* ema_count = (const float*)d_in[3];
  const float* ema_weight = (const float*)d_in[4];
  float* out = (float*)d_out;

  float* ws = (float*)d_ws;
  size_t off = 0;
  float* dotbuf = ws + off; off += (size_t)NROWS * MC;   // 16M floats
  float* esq   = ws + off; off += MC;
  float* xsq_a = ws + off; off += NROWS;
  float* xsq_v = ws + off; off += NROWS;
  float* a_adj = ws + off; off += NROWS;
  float* v_adj = ws + off; off += NROWS;
  int* a_idx = (int*)(ws + off); off += NROWS;
  int* v_idx = (int*)(ws + off); off += NROWS;
  float* cnt_a = ws + off; off += MC;
  float* cnt_v = ws + off; off += MC;
  float* acc_a = ws + off; off += (size_t)MC * DIM;
  float* acc_v = ws + off; off += (size_t)MC * DIM;
  float* ec = ws + off; off += MC;
  float* en = ws + off; off += (size_t)MC * DIM;
  float* lacc = ws + off; off += 4;

  // zero: cnt_a, cnt_v, acc_a, acc_v are contiguous; plus loss accumulators
  hipMemsetAsync(cnt_a, 0, (size_t)(2 * MC + 2 * (size_t)MC * DIM) * sizeof(float), stream);
  hipMemsetAsync(lacc, 0, 4 * sizeof(float), stream);

  const dim3 b256(256);
  const dim3 ggrid(MC / 64, NROWS / 64);

  rowsq<<<MC / 4, b256, 0, stream>>>(emb, esq, MC);
  rowsq<<<NROWS / 4, b256, 0, stream>>>(audio, xsq_a, NROWS);
  rowsq<<<NROWS / 4, b256, 0, stream>>>(video, xsq_v, NROWS);

  gemm_nt<<<ggrid, b256, 0, stream>>>(audio, emb, dotbuf);
  scan_dist<<<NROWS / 4, b256, 0, stream>>>(dotbuf, esq, xsq_a, a_idx, a_adj);
  gemm_nt<<<ggrid, b256, 0, stream>>>(video, emb, dotbuf);
  scan_dist<<<NROWS / 4, b256, 0, stream>>>(dotbuf, esq, xsq_v, v_idx, v_adj);

  scatter_ema<<<NROWS, b256, 0, stream>>>(audio, video, a_idx, a_adj, v_idx, v_adj, acc_a, acc_v,
                                          cnt_a, cnt_v);
  ec_kernel<<<1, 1024, 0, stream>>>(ema_count, cnt_v, cnt_a, ec);
  en_kernel<<<MC, b256, 0, stream>>>(ema_weight, acc_v, acc_a, ec, en);

  gemm_nt<<<ggrid, b256, 0, stream>>>(audio, en, dotbuf);
  scan_nce<<<NROWS / 4, b256, 0, stream>>>(dotbuf, xsq_a, a_idx, v_idx, lacc + 0);
  gemm_nt<<<ggrid, b256, 0, stream>>>(video, en, dotbuf);
  scan_nce<<<NROWS / 4, b256, 0, stream>>>(dotbuf, xsq_v, v_idx, a_idx, lacc + 2);

  finalize<<<1, 1, 0, stream>>>(lacc, out);
}

// Round 2
// 497.641 us; speedup vs baseline: 1.9102x; 1.9102x over previous
//
#include <hip/hip_runtime.h>
#include <math.h>

#define NROWS 16384
#define DIM 256
#define MC 1024

constexpr float kDecay = 0.99f;
constexpr float kEps = 1e-5f;
constexpr float kTemp = 0.1f;
constexpr float kCommit = 0.25f;
constexpr float kMaxEnt = 6.93147180559945f; // ln(1024)

using short8 = __attribute__((ext_vector_type(8))) short;
using f32x4 = __attribute__((ext_vector_type(4))) float;

__device__ __forceinline__ float wave_sum(float v) {
#pragma unroll
  for (int off = 32; off > 0; off >>= 1) v += __shfl_xor(v, off);
  return v;
}
__device__ __forceinline__ float wave_max(float v) {
#pragma unroll
  for (int off = 32; off > 0; off >>= 1) v = fmaxf(v, __shfl_xor(v, off));
  return v;
}

__device__ __forceinline__ unsigned short f2bf(float f) {
  union { float f; unsigned int u; } c;
  c.f = f;
  const unsigned int u = c.u;
  return (unsigned short)((u + 0x7FFFu + ((u >> 16) & 1u)) >> 16);  // RNE
}

// fused: bf16 copy + row sum-of-squares. one wave per row (DIM=256 = 64 lanes * 4)
__global__ __launch_bounds__(256) void convert_rowsq(const float* __restrict__ X,
                                                     unsigned short* __restrict__ Xb,
                                                     float* __restrict__ sq, int nrows) {
  const int row = (int)((blockIdx.x * blockDim.x + threadIdx.x) >> 6);
  const int lane = threadIdx.x & 63;
  if (row >= nrows) return;
  const float4 x = *reinterpret_cast<const float4*>(X + (size_t)row * DIM + (lane << 2));
  float s = x.x * x.x + x.y * x.y + x.z * x.z + x.w * x.w;
  ushort4 b;
  b.x = f2bf(x.x); b.y = f2bf(x.y); b.z = f2bf(x.z); b.w = f2bf(x.w);
  *reinterpret_cast<ushort4*>(Xb + (size_t)row * DIM + (lane << 2)) = b;
  s = wave_sum(s);
  if (lane == 0) sq[row] = s;
}

// C[r][c] = sum_k X[r][k]*W[c][k], X:[NROWS][256] bf16, W:[1024][256] bf16, C fp32.
// 128x128 tile, BK=64, 4 waves (2x2), each wave 64x64 via 4x4 frags of 16x16x32 MFMA.
#define GBM 128
#define GBK 64
#define LDK 72  // pad 64->72 elems (144B rows): spreads frag reads over 8 bank slots
__global__ __launch_bounds__(256) void gemm_bf16(const unsigned short* __restrict__ X,
                                                 const unsigned short* __restrict__ W,
                                                 float* __restrict__ C) {
  __shared__ unsigned short As[GBM][LDK];
  __shared__ unsigned short Bs[GBM][LDK];
  const int tid = threadIdx.x;
  const int l = tid & 63;
  const int w = tid >> 6;
  const int wr = w >> 1, wc = w & 1;
  const int row0 = blockIdx.y * GBM;
  const int col0 = blockIdx.x * GBM;
  f32x4 acc[4][4] = {};
  for (int k0 = 0; k0 < DIM; k0 += GBK) {
#pragma unroll
    for (int j = 0; j < 4; ++j) {
      const int c = j * 256 + tid;       // 0..1023 chunks of 8 bf16
      const int r = c >> 3, cc = (c & 7) << 3;
      const short8 av = *reinterpret_cast<const short8*>(X + (size_t)(row0 + r) * DIM + k0 + cc);
      const short8 bv = *reinterpret_cast<const short8*>(W + (size_t)(col0 + r) * DIM + k0 + cc);
      *reinterpret_cast<short8*>(&As[r][cc]) = av;
      *reinterpret_cast<short8*>(&Bs[r][cc]) = bv;
    }
    __syncthreads();
#pragma unroll
    for (int ks = 0; ks < 2; ++ks) {
      short8 af[4], bfr[4];
#pragma unroll
      for (int m = 0; m < 4; ++m)
        af[m] = *reinterpret_cast<const short8*>(&As[wr * 64 + m * 16 + (l & 15)][ks * 32 + (l >> 4) * 8]);
#pragma unroll
      for (int n = 0; n < 4; ++n)
        bfr[n] = *reinterpret_cast<const short8*>(&Bs[wc * 64 + n * 16 + (l & 15)][ks * 32 + (l >> 4) * 8]);
#pragma unroll
      for (int m = 0; m < 4; ++m)
#pragma unroll
        for (int n = 0; n < 4; ++n)
          acc[m][n] = __builtin_amdgcn_mfma_f32_16x16x32_bf16(af[m], bfr[n], acc[m][n], 0, 0, 0);
    }
    __syncthreads();
  }
  // C/D layout: col = lane&15, row = (lane>>4)*4 + reg
  const int lr = (l >> 4) << 2, lc = l & 15;
#pragma unroll
  for (int m = 0; m < 4; ++m)
#pragma unroll
    for (int n = 0; n < 4; ++n) {
      float* cp = C + (size_t)(row0 + wr * 64 + m * 16 + lr) * MC + col0 + wc * 64 + n * 16 + lc;
#pragma unroll
      for (int r = 0; r < 4; ++r) cp[(size_t)r * MC] = acc[m][n][r];
    }
}

// per-row: dist = esq + xsq - 2*dot; argmin (first index on ties),
// entropy of softmax(-sqrt(max(dist,0))) with log(p+1e-5); adj = 1 - H/lnM
__global__ __launch_bounds__(256) void scan_dist(const float* __restrict__ dot,
                                                 const float* __restrict__ esq,
                                                 const float* __restrict__ xsq,
                                                 int* __restrict__ idx_out,
                                                 float* __restrict__ adj_out) {
  const int row = (int)((blockIdx.x * blockDim.x + threadIdx.x) >> 6);
  const int lane = threadIdx.x & 63;
  const float* drow = dot + (size_t)row * MC;
  const float xs = xsq[row];
  float sv[16];
  float bestv = INFINITY;
  int besti = MC;
  float smax = -INFINITY;
#pragma unroll
  for (int j = 0; j < 16; ++j) {
    const int m = lane + (j << 6);
    const float dv = esq[m] + xs - 2.0f * drow[m];
    if (dv < bestv || (dv == bestv && m < besti)) { bestv = dv; besti = m; }
    const float s = -sqrtf(fmaxf(dv, 0.0f));
    sv[j] = s;
    smax = fmaxf(smax, s);
  }
#pragma unroll
  for (int off = 32; off > 0; off >>= 1) {
    const float ov = __shfl_xor(bestv, off);
    const int oi = __shfl_xor(besti, off);
    if (ov < bestv || (ov == bestv && oi < besti)) { bestv = ov; besti = oi; }
    smax = fmaxf(smax, __shfl_xor(smax, off));
  }
  float se = 0.f;
#pragma unroll
  for (int j = 0; j < 16; ++j) se += expf(sv[j] - smax);
  se = wave_sum(se);
  float H = 0.f;
#pragma unroll
  for (int j = 0; j < 16; ++j) {
    const float p = expf(sv[j] - smax) / se;
    H -= p * logf(p + 1e-5f);
  }
  H = wave_sum(H);
  if (lane == 0) {
    idx_out[row] = besti;
    adj_out[row] = 1.0f - H / kMaxEnt;
  }
}

// EMA scatter: one block per row
__global__ __launch_bounds__(256) void scatter_ema(
    const float* __restrict__ a, const float* __restrict__ v, const int* __restrict__ aidx,
    const float* __restrict__ aadj, const int* __restrict__ vidx, const float* __restrict__ vadj,
    float* __restrict__ acc_a, float* __restrict__ acc_v, float* __restrict__ cnt_a,
    float* __restrict__ cnt_v) {
  const int row = blockIdx.x;
  const int d = threadIdx.x;
  const size_t o = (size_t)row * DIM + d;
  const float s = a[o] + v[o];
  const int ia = aidx[row], iv = vidx[row];
  const float wa = aadj[row], wv = vadj[row];
  atomicAdd(acc_a + (size_t)ia * DIM + d, wa * s);
  atomicAdd(acc_v + (size_t)iv * DIM + d, wv * s);
  if (d == 0) {
    atomicAdd(cnt_a + ia, wa);
    atomicAdd(cnt_v + iv, wv);
  }
}

// two-pass EMA count update with Laplace smoothing; single block of 1024
__global__ __launch_bounds__(1024) void ec_kernel(const float* __restrict__ ema_count,
                                                  const float* __restrict__ cnt_v,
                                                  const float* __restrict__ cnt_a,
                                                  float* __restrict__ ec_out) {
  __shared__ float red[1024];
  const int m = threadIdx.x;
  float ec = kDecay * ema_count[m] + (1.f - kDecay) * cnt_v[m];
  red[m] = ec;
  __syncthreads();
  for (int s = 512; s > 0; s >>= 1) {
    if (m < s) red[m] += red[m + s];
    __syncthreads();
  }
  float n = red[0];
  __syncthreads();
  ec = (ec + kEps) / (n + MC * kEps) * n;
  ec = kDecay * ec + (1.f - kDecay) * cnt_a[m];
  red[m] = ec;
  __syncthreads();
  for (int s = 512; s > 0; s >>= 1) {
    if (m < s) red[m] += red[m + s];
    __syncthreads();
  }
  n = red[0];
  ec = (ec + kEps) / (n + MC * kEps) * n;
  ec_out[m] = ec;
}

// emb_new = ew2/ec; en = row-normalized, emitted as bf16. one block per code
__global__ __launch_bounds__(256) void en_kernel(const float* __restrict__ ema_weight,
                                                 const float* __restrict__ acc_v,
                                                 const float* __restrict__ acc_a,
                                                 const float* __restrict__ ec,
                                                 unsigned short* __restrict__ en_b) {
  const int mcode = blockIdx.x;
  const int d = threadIdx.x;
  const size_t o = (size_t)mcode * DIM + d;
  float ew = kDecay * ema_weight[o] + 0.5f * (1.f - kDecay) * acc_v[o];
  ew = kDecay * ew + 0.5f * (1.f - kDecay) * acc_a[o];
  const float e = ew / ec[mcode];
  __shared__ float red[256];
  red[d] = e * e;
  __syncthreads();
  for (int s = 128; s > 0; s >>= 1) {
    if (d < s) red[d] += red[d + s];
    __syncthreads();
  }
  const float nrm = sqrtf(red[0]);
  en_b[o] = f2bf(e / fmaxf(nrm, 1e-8f));
}

// per-row logsumexp of dot*inv; accumulate (l[self]-lse) and (l[coup]-lse)
__global__ __launch_bounds__(256) void scan_nce(const float* __restrict__ dot,
                                                const float* __restrict__ xsq,
                                                const int* __restrict__ sidx,
                                                const int* __restrict__ cidx,
                                                float* __restrict__ acc2) {
  __shared__ float part[8];
  const int row = (int)((blockIdx.x * blockDim.x + threadIdx.x) >> 6);
  const int lane = threadIdx.x & 63;
  const int wib = threadIdx.x >> 6;
  const float* drow = dot + (size_t)row * MC;
  const float inv = 1.0f / (fmaxf(sqrtf(xsq[row]), 1e-8f) * kTemp);
  float l[16];
  float lmax = -INFINITY;
#pragma unroll
  for (int j = 0; j < 16; ++j) {
    l[j] = drow[lane + (j << 6)] * inv;
    lmax = fmaxf(lmax, l[j]);
  }
  lmax = wave_max(lmax);
  float se = 0.f;
#pragma unroll
  for (int j = 0; j < 16; ++j) se += expf(l[j] - lmax);
  se = wave_sum(se);
  const float lse = lmax + logf(se);
  const int si = sidx[row], ci = cidx[row];
  float st = 0.f, ct = 0.f;
#pragma unroll
  for (int j = 0; j < 16; ++j) {
    const int m = lane + (j << 6);
    if (m == si) st = l[j] - lse;
    if (m == ci) ct = l[j] - lse;
  }
  st = wave_sum(st);
  ct = wave_sum(ct);
  if (lane == 0) {
    part[wib] = st;
    part[4 + wib] = ct;
  }
  __syncthreads();
  if (threadIdx.x == 0) {
    atomicAdd(acc2 + 0, part[0] + part[1] + part[2] + part[3]);
    atomicAdd(acc2 + 1, part[4] + part[5] + part[6] + part[7]);
  }
}

__global__ void finalize(const float* __restrict__ acc4, float* __restrict__ out) {
  const float invN = 1.0f / (float)NROWS;
  const float ce_as = -acc4[0] * invN, ce_ac = -acc4[1] * invN;
  const float ce_vs = -acc4[2] * invN, ce_vc = -acc4[3] * invN;
  const float a_cpcl = kCommit * ce_as + (1.f - kCommit) * ce_ac;
  const float v_cpcl = kCommit * ce_vs + (1.f - kCommit) * ce_vc;
  out[0] = (kCommit * a_cpcl + kCommit * v_cpcl) / 32.0f;
}

extern "C" void kernel_launch(void* const* d_in, const int* in_sizes, int n_in, void* d_out,
                              int out_size, void* d_ws, size_t ws_size, hipStream_t stream) {
  const float* audio = (const float*)d_in[0];
  const float* video = (const float*)d_in[1];
  const float* emb = (const float*)d_in[2];
  const float* ema_count = (const float*)d_in[3];
  const float* ema_weight = (const float*)d_in[4];
  float* out = (float*)d_out;

  float* ws = (float*)d_ws;
  size_t off = 0;
  float* dotbuf = ws + off; off += (size_t)NROWS * MC;   // 16M floats
  float* esq   = ws + off; off += MC;
  float* xsq_a = ws + off; off += NROWS;
  float* xsq_v = ws + off; off += NROWS;
  float* a_adj = ws + off; off += NROWS;
  float* v_adj = ws + off; off += NROWS;
  int* a_idx = (int*)(ws + off); off += NROWS;
  int* v_idx = (int*)(ws + off); off += NROWS;
  float* cnt_a = ws + off; off += MC;
  float* cnt_v = ws + off; off += MC;
  float* acc_a = ws + off; off += (size_t)MC * DIM;
  float* acc_v = ws + off; off += (size_t)MC * DIM;
  float* ec = ws + off; off += MC;
  float* lacc = ws + off; off += 4 + 60;  // keep 16B alignment for what follows
  unsigned short* a_bf = (unsigned short*)(ws + off); off += (size_t)NROWS * DIM / 2;
  unsigned short* v_bf = (unsigned short*)(ws + off); off += (size_t)NROWS * DIM / 2;
  unsigned short* e_bf = (unsigned short*)(ws + off); off += (size_t)MC * DIM / 2;
  unsigned short* en_bf = (unsigned short*)(ws + off); off += (size_t)MC * DIM / 2;

  hipMemsetAsync(cnt_a, 0, (size_t)(2 * MC + 2 * (size_t)MC * DIM) * sizeof(float), stream);
  hipMemsetAsync(lacc, 0, 4 * sizeof(float), stream);

  const dim3 b256(256);
  const dim3 ggrid(MC / GBM, NROWS / GBM);

  convert_rowsq<<<MC / 4, b256, 0, stream>>>(emb, e_bf, esq, MC);
  convert_rowsq<<<NROWS / 4, b256, 0, stream>>>(audio, a_bf, xsq_a, NROWS);
  convert_rowsq<<<NROWS / 4, b256, 0, stream>>>(video, v_bf, xsq_v, NROWS);

  gemm_bf16<<<ggrid, b256, 0, stream>>>(a_bf, e_bf, dotbuf);
  scan_dist<<<NROWS / 4, b256, 0, stream>>>(dotbuf, esq, xsq_a, a_idx, a_adj);
  gemm_bf16<<<ggrid, b256, 0, stream>>>(v_bf, e_bf, dotbuf);
  scan_dist<<<NROWS / 4, b256, 0, stream>>>(dotbuf, esq, xsq_v, v_idx, v_adj);

  scatter_ema<<<NROWS, b256, 0, stream>>>(audio, video, a_idx, a_adj, v_idx, v_adj, acc_a, acc_v,
                                          cnt_a, cnt_v);
  ec_kernel<<<1, 1024, 0, stream>>>(ema_count, cnt_v, cnt_a, ec);
  en_kernel<<<MC, b256, 0, stream>>>(ema_weight, acc_v, acc_a, ec, en_bf);

  gemm_bf16<<<ggrid, b256, 0, stream>>>(a_bf, en_bf, dotbuf);
  scan_nce<<<NROWS / 4, b256, 0, stream>>>(dotbuf, xsq_a, a_idx, v_idx, lacc + 0);
  gemm_bf16<<<ggrid, b256, 0, stream>>>(v_bf, en_bf, dotbuf);
  scan_nce<<<NROWS / 4, b256, 0, stream>>>(dotbuf, xsq_v, v_idx, a_idx, lacc + 2);

  finalize<<<1, 1, 0, stream>>>(lacc, out);
}

// Round 3
// 279.302 us; speedup vs baseline: 3.4034x; 1.7817x over previous
//
#include <hip/hip_runtime.h>
#include <math.h>

#define NROWS 16384
#define DIM 256
#define MC 1024

constexpr float kDecay = 0.99f;
constexpr float kEps = 1e-5f;
constexpr float kTemp = 0.1f;
constexpr float kCommit = 0.25f;
constexpr float kMaxEnt = 6.93147180559945f; // ln(1024)

using short8 = __attribute__((ext_vector_type(8))) short;
using f32x4 = __attribute__((ext_vector_type(4))) float;

__device__ __forceinline__ float wave_sum(float v) {
#pragma unroll
  for (int off = 32; off > 0; off >>= 1) v += __shfl_xor(v, off);
  return v;
}
__device__ __forceinline__ float wave_max(float v) {
#pragma unroll
  for (int off = 32; off > 0; off >>= 1) v = fmaxf(v, __shfl_xor(v, off));
  return v;
}

__device__ __forceinline__ unsigned short f2bf(float f) {
  union { float f; unsigned int u; } c;
  c.f = f;
  const unsigned int u = c.u;
  return (unsigned short)((u + 0x7FFFu + ((u >> 16) & 1u)) >> 16);  // RNE
}

// fused: bf16 copy + row sum-of-squares. one wave per row (DIM=256 = 64 lanes * 4)
__global__ __launch_bounds__(256) void convert_rowsq(const float* __restrict__ X,
                                                     unsigned short* __restrict__ Xb,
                                                     float* __restrict__ sq, int nrows) {
  const int row = (int)((blockIdx.x * blockDim.x + threadIdx.x) >> 6);
  const int lane = threadIdx.x & 63;
  if (row >= nrows) return;
  const float4 x = *reinterpret_cast<const float4*>(X + (size_t)row * DIM + (lane << 2));
  float s = x.x * x.x + x.y * x.y + x.z * x.z + x.w * x.w;
  ushort4 b;
  b.x = f2bf(x.x); b.y = f2bf(x.y); b.z = f2bf(x.z); b.w = f2bf(x.w);
  *reinterpret_cast<ushort4*>(Xb + (size_t)row * DIM + (lane << 2)) = b;
  s = wave_sum(s);
  if (lane == 0) sq[row] = s;
}

// C[r][c] = sum_k X[r][k]*W[c][k], X:[NROWS][256] bf16, W:[1024][256] bf16, C fp32.
// 128x128 tile, BK=64, 4 waves (2x2), each wave 64x64 via 4x4 frags of 16x16x32 MFMA.
#define GBM 128
#define GBK 64
#define LDK 72  // pad 64->72 elems (144B rows): spreads frag reads over 8 bank slots
__global__ __launch_bounds__(256) void gemm_bf16(const unsigned short* __restrict__ X,
                                                 const unsigned short* __restrict__ W,
                                                 float* __restrict__ C) {
  __shared__ unsigned short As[GBM][LDK];
  __shared__ unsigned short Bs[GBM][LDK];
  const int tid = threadIdx.x;
  const int l = tid & 63;
  const int w = tid >> 6;
  const int wr = w >> 1, wc = w & 1;
  const int row0 = blockIdx.y * GBM;
  const int col0 = blockIdx.x * GBM;
  f32x4 acc[4][4] = {};
  for (int k0 = 0; k0 < DIM; k0 += GBK) {
#pragma unroll
    for (int j = 0; j < 4; ++j) {
      const int c = j * 256 + tid;       // 0..1023 chunks of 8 bf16
      const int r = c >> 3, cc = (c & 7) << 3;
      const short8 av = *reinterpret_cast<const short8*>(X + (size_t)(row0 + r) * DIM + k0 + cc);
      const short8 bv = *reinterpret_cast<const short8*>(W + (size_t)(col0 + r) * DIM + k0 + cc);
      *reinterpret_cast<short8*>(&As[r][cc]) = av;
      *reinterpret_cast<short8*>(&Bs[r][cc]) = bv;
    }
    __syncthreads();
#pragma unroll
    for (int ks = 0; ks < 2; ++ks) {
      short8 af[4], bfr[4];
#pragma unroll
      for (int m = 0; m < 4; ++m)
        af[m] = *reinterpret_cast<const short8*>(&As[wr * 64 + m * 16 + (l & 15)][ks * 32 + (l >> 4) * 8]);
#pragma unroll
      for (int n = 0; n < 4; ++n)
        bfr[n] = *reinterpret_cast<const short8*>(&Bs[wc * 64 + n * 16 + (l & 15)][ks * 32 + (l >> 4) * 8]);
#pragma unroll
      for (int m = 0; m < 4; ++m)
#pragma unroll
        for (int n = 0; n < 4; ++n)
          acc[m][n] = __builtin_amdgcn_mfma_f32_16x16x32_bf16(af[m], bfr[n], acc[m][n], 0, 0, 0);
    }
    __syncthreads();
  }
  // C/D layout: col = lane&15, row = (lane>>4)*4 + reg
  const int lr = (l >> 4) << 2, lc = l & 15;
#pragma unroll
  for (int m = 0; m < 4; ++m)
#pragma unroll
    for (int n = 0; n < 4; ++n) {
      float* cp = C + (size_t)(row0 + wr * 64 + m * 16 + lr) * MC + col0 + wc * 64 + n * 16 + lc;
#pragma unroll
      for (int r = 0; r < 4; ++r) cp[(size_t)r * MC] = acc[m][n][r];
    }
}

// per-row: dist = esq + xsq - 2*dot; argmin (first index on ties);
// entropy H = lse - sum(p*s) - M*1e-5  (analytic form of -sum p*log(p+1e-5),
// valid since p >= ~6e-5 >> 1e-5; residual < ~1e-4); adj = 1 - H/lnM
__global__ __launch_bounds__(256) void scan_dist(const float* __restrict__ dot,
                                                 const float* __restrict__ esq,
                                                 const float* __restrict__ xsq,
                                                 int* __restrict__ idx_out,
                                                 float* __restrict__ adj_out) {
  const int row = (int)((blockIdx.x * blockDim.x + threadIdx.x) >> 6);
  const int lane = threadIdx.x & 63;
  const float* drow = dot + (size_t)row * MC;
  const float xs = xsq[row];
  float sv[16];
  float bestv = INFINITY;
  int besti = MC;
  float smax = -INFINITY;
#pragma unroll
  for (int q = 0; q < 4; ++q) {
    const int m0 = q * 256 + (lane << 2);
    const float4 d4 = *reinterpret_cast<const float4*>(drow + m0);
    const float4 e4 = *reinterpret_cast<const float4*>(esq + m0);
    const float dv[4] = {e4.x + xs - 2.0f * d4.x, e4.y + xs - 2.0f * d4.y,
                         e4.z + xs - 2.0f * d4.z, e4.w + xs - 2.0f * d4.w};
#pragma unroll
    for (int c = 0; c < 4; ++c) {
      if (dv[c] < bestv) { bestv = dv[c]; besti = m0 + c; }
      const float s = -sqrtf(fmaxf(dv[c], 0.0f));
      sv[(q << 2) + c] = s;
      smax = fmaxf(smax, s);
    }
  }
#pragma unroll
  for (int off = 32; off > 0; off >>= 1) {
    const float ov = __shfl_xor(bestv, off);
    const int oi = __shfl_xor(besti, off);
    if (ov < bestv || (ov == bestv && oi < besti)) { bestv = ov; besti = oi; }
    smax = fmaxf(smax, __shfl_xor(smax, off));
  }
  float se = 0.f, ws = 0.f;
#pragma unroll
  for (int j = 0; j < 16; ++j) {
    const float e = expf(sv[j] - smax);
    se += e;
    ws += e * sv[j];
  }
  se = wave_sum(se);
  ws = wave_sum(ws);
  if (lane == 0) {
    const float H = smax + logf(se) - ws / se - 1e-5f * (float)MC;
    idx_out[row] = besti;
    adj_out[row] = 1.0f - H / kMaxEnt;
  }
}

// EMA scatter: one block per row
__global__ __launch_bounds__(256) void scatter_ema(
    const float* __restrict__ a, const float* __restrict__ v, const int* __restrict__ aidx,
    const float* __restrict__ aadj, const int* __restrict__ vidx, const float* __restrict__ vadj,
    float* __restrict__ acc_a, float* __restrict__ acc_v, float* __restrict__ cnt_a,
    float* __restrict__ cnt_v) {
  const int row = blockIdx.x;
  const int d = threadIdx.x;
  const size_t o = (size_t)row * DIM + d;
  const float s = a[o] + v[o];
  const int ia = aidx[row], iv = vidx[row];
  const float wa = aadj[row], wv = vadj[row];
  atomicAdd(acc_a + (size_t)ia * DIM + d, wa * s);
  atomicAdd(acc_v + (size_t)iv * DIM + d, wv * s);
  if (d == 0) {
    atomicAdd(cnt_a + ia, wa);
    atomicAdd(cnt_v + iv, wv);
  }
}

// two-pass EMA count update with Laplace smoothing; single block of 1024
__global__ __launch_bounds__(1024) void ec_kernel(const float* __restrict__ ema_count,
                                                  const float* __restrict__ cnt_v,
                                                  const float* __restrict__ cnt_a,
                                                  float* __restrict__ ec_out) {
  __shared__ float red[1024];
  const int m = threadIdx.x;
  float ec = kDecay * ema_count[m] + (1.f - kDecay) * cnt_v[m];
  red[m] = ec;
  __syncthreads();
  for (int s = 512; s > 0; s >>= 1) {
    if (m < s) red[m] += red[m + s];
    __syncthreads();
  }
  float n = red[0];
  __syncthreads();
  ec = (ec + kEps) / (n + MC * kEps) * n;
  ec = kDecay * ec + (1.f - kDecay) * cnt_a[m];
  red[m] = ec;
  __syncthreads();
  for (int s = 512; s > 0; s >>= 1) {
    if (m < s) red[m] += red[m + s];
    __syncthreads();
  }
  n = red[0];
  ec = (ec + kEps) / (n + MC * kEps) * n;
  ec_out[m] = ec;
}

// emb_new = ew2/ec; en = row-normalized, emitted as bf16. one block per code
__global__ __launch_bounds__(256) void en_kernel(const float* __restrict__ ema_weight,
                                                 const float* __restrict__ acc_v,
                                                 const float* __restrict__ acc_a,
                                                 const float* __restrict__ ec,
                                                 unsigned short* __restrict__ en_b) {
  const int mcode = blockIdx.x;
  const int d = threadIdx.x;
  const size_t o = (size_t)mcode * DIM + d;
  float ew = kDecay * ema_weight[o] + 0.5f * (1.f - kDecay) * acc_v[o];
  ew = kDecay * ew + 0.5f * (1.f - kDecay) * acc_a[o];
  const float e = ew / ec[mcode];
  __shared__ float red[256];
  red[d] = e * e;
  __syncthreads();
  for (int s = 128; s > 0; s >>= 1) {
    if (d < s) red[d] += red[d + s];
    __syncthreads();
  }
  const float nrm = sqrtf(red[0]);
  en_b[o] = f2bf(e / fmaxf(nrm, 1e-8f));
}

// per-row logsumexp of dot*inv; per-block partials (NO atomics):
// part[b] = sum over block rows of (l[self]-lse); part[4096+b] = same for coupled
__global__ __launch_bounds__(256) void scan_nce(const float* __restrict__ dot,
                                                const float* __restrict__ xsq,
                                                const int* __restrict__ sidx,
                                                const int* __restrict__ cidx,
                                                float* __restrict__ part) {
  __shared__ float sp[8];
  const int row = (int)((blockIdx.x * blockDim.x + threadIdx.x) >> 6);
  const int lane = threadIdx.x & 63;
  const int wib = threadIdx.x >> 6;
  const float* drow = dot + (size_t)row * MC;
  const float inv = 1.0f / (fmaxf(sqrtf(xsq[row]), 1e-8f) * kTemp);
  float l[16];
  float lmax = -INFINITY;
#pragma unroll
  for (int q = 0; q < 4; ++q) {
    const float4 d4 = *reinterpret_cast<const float4*>(drow + q * 256 + (lane << 2));
    l[(q << 2) + 0] = d4.x * inv; l[(q << 2) + 1] = d4.y * inv;
    l[(q << 2) + 2] = d4.z * inv; l[(q << 2) + 3] = d4.w * inv;
#pragma unroll
    for (int c = 0; c < 4; ++c) lmax = fmaxf(lmax, l[(q << 2) + c]);
  }
  lmax = wave_max(lmax);
  float se = 0.f;
#pragma unroll
  for (int j = 0; j < 16; ++j) se += expf(l[j] - lmax);
  se = wave_sum(se);
  if (lane == 0) {
    const float lse = lmax + logf(se);
    sp[wib] = drow[sidx[row]] * inv - lse;
    sp[4 + wib] = drow[cidx[row]] * inv - lse;
  }
  __syncthreads();
  if (threadIdx.x == 0) {
    part[blockIdx.x] = sp[0] + sp[1] + sp[2] + sp[3];
    part[4096 + blockIdx.x] = sp[4] + sp[5] + sp[6] + sp[7];
  }
}

// reduce 2x(4096+4096) partials and emit the scalar loss. 1 block x 1024.
__global__ __launch_bounds__(1024) void finalize(const float* __restrict__ pa,
                                                 const float* __restrict__ pv,
                                                 float* __restrict__ out) {
  const int tid = threadIdx.x;
  const int lane = tid & 63;
  const int wid = tid >> 6;
  float sa = 0.f, ca = 0.f, sv = 0.f, cv = 0.f;
  for (int i = tid; i < 4096; i += 1024) {
    sa += pa[i]; ca += pa[4096 + i];
    sv += pv[i]; cv += pv[4096 + i];
  }
  sa = wave_sum(sa); ca = wave_sum(ca); sv = wave_sum(sv); cv = wave_sum(cv);
  __shared__ float red[16][4];
  if (lane == 0) { red[wid][0] = sa; red[wid][1] = ca; red[wid][2] = sv; red[wid][3] = cv; }
  __syncthreads();
  if (tid == 0) {
    float t0 = 0.f, t1 = 0.f, t2 = 0.f, t3 = 0.f;
#pragma unroll
    for (int i = 0; i < 16; ++i) { t0 += red[i][0]; t1 += red[i][1]; t2 += red[i][2]; t3 += red[i][3]; }
    const float invN = 1.0f / (float)NROWS;
    const float ce_as = -t0 * invN, ce_ac = -t1 * invN;
    const float ce_vs = -t2 * invN, ce_vc = -t3 * invN;
    const float a_cpcl = kCommit * ce_as + (1.f - kCommit) * ce_ac;
    const float v_cpcl = kCommit * ce_vs + (1.f - kCommit) * ce_vc;
    out[0] = (kCommit * a_cpcl + kCommit * v_cpcl) / 32.0f;
  }
}

extern "C" void kernel_launch(void* const* d_in, const int* in_sizes, int n_in, void* d_out,
                              int out_size, void* d_ws, size_t ws_size, hipStream_t stream) {
  const float* audio = (const float*)d_in[0];
  const float* video = (const float*)d_in[1];
  const float* emb = (const float*)d_in[2];
  const float* ema_count = (const float*)d_in[3];
  const float* ema_weight = (const float*)d_in[4];
  float* out = (float*)d_out;

  float* ws = (float*)d_ws;
  size_t off = 0;
  float* dotbuf = ws + off; off += (size_t)NROWS * MC;   // 16M floats
  float* esq   = ws + off; off += MC;
  float* xsq_a = ws + off; off += NROWS;
  float* xsq_v = ws + off; off += NROWS;
  float* a_adj = ws + off; off += NROWS;
  float* v_adj = ws + off; off += NROWS;
  int* a_idx = (int*)(ws + off); off += NROWS;
  int* v_idx = (int*)(ws + off); off += NROWS;
  float* cnt_a = ws + off; off += MC;
  float* cnt_v = ws + off; off += MC;
  float* acc_a = ws + off; off += (size_t)MC * DIM;
  float* acc_v = ws + off; off += (size_t)MC * DIM;
  float* ec = ws + off; off += MC;
  float* part_a = ws + off; off += 8192;
  float* part_v = ws + off; off += 8192;
  unsigned short* a_bf = (unsigned short*)(ws + off); off += (size_t)NROWS * DIM / 2;
  unsigned short* v_bf = (unsigned short*)(ws + off); off += (size_t)NROWS * DIM / 2;
  unsigned short* e_bf = (unsigned short*)(ws + off); off += (size_t)MC * DIM / 2;
  unsigned short* en_bf = (unsigned short*)(ws + off); off += (size_t)MC * DIM / 2;

  hipMemsetAsync(cnt_a, 0, (size_t)(2 * MC + 2 * (size_t)MC * DIM) * sizeof(float), stream);

  const dim3 b256(256);
  const dim3 ggrid(MC / GBM, NROWS / GBM);

  convert_rowsq<<<MC / 4, b256, 0, stream>>>(emb, e_bf, esq, MC);
  convert_rowsq<<<NROWS / 4, b256, 0, stream>>>(audio, a_bf, xsq_a, NROWS);
  convert_rowsq<<<NROWS / 4, b256, 0, stream>>>(video, v_bf, xsq_v, NROWS);

  gemm_bf16<<<ggrid, b256, 0, stream>>>(a_bf, e_bf, dotbuf);
  scan_dist<<<NROWS / 4, b256, 0, stream>>>(dotbuf, esq, xsq_a, a_idx, a_adj);
  gemm_bf16<<<ggrid, b256, 0, stream>>>(v_bf, e_bf, dotbuf);
  scan_dist<<<NROWS / 4, b256, 0, stream>>>(dotbuf, esq, xsq_v, v_idx, v_adj);

  scatter_ema<<<NROWS, b256, 0, stream>>>(audio, video, a_idx, a_adj, v_idx, v_adj, acc_a, acc_v,
                                          cnt_a, cnt_v);
  ec_kernel<<<1, 1024, 0, stream>>>(ema_count, cnt_v, cnt_a, ec);
  en_kernel<<<MC, b256, 0, stream>>>(ema_weight, acc_v, acc_a, ec, en_bf);

  gemm_bf16<<<ggrid, b256, 0, stream>>>(a_bf, en_bf, dotbuf);
  scan_nce<<<NROWS / 4, b256, 0, stream>>>(dotbuf, xsq_a, a_idx, v_idx, part_a);
  gemm_bf16<<<ggrid, b256, 0, stream>>>(v_bf, en_bf, dotbuf);
  scan_nce<<<NROWS / 4, b256, 0, stream>>>(dotbuf, xsq_v, v_idx, a_idx, part_v);

  finalize<<<1, 1024, 0, stream>>>(part_a, part_v, out);
}

// Round 4
// 254.220 us; speedup vs baseline: 3.7392x; 1.0987x over previous
//
#include <hip/hip_runtime.h>
#include <math.h>

#define NROWS 16384
#define NR2 32768  // audio ++ video
#define DIM 256
#define MC 1024

constexpr float kDecay = 0.99f;
constexpr float kEps = 1e-5f;
constexpr float kTemp = 0.1f;
constexpr float kCommit = 0.25f;
constexpr float kMaxEnt = 6.93147180559945f; // ln(1024)

using short8 = __attribute__((ext_vector_type(8))) short;
using f32x4 = __attribute__((ext_vector_type(4))) float;

__device__ __forceinline__ float wave_sum(float v) {
#pragma unroll
  for (int off = 32; off > 0; off >>= 1) v += __shfl_xor(v, off);
  return v;
}
__device__ __forceinline__ float wave_max(float v) {
#pragma unroll
  for (int off = 32; off > 0; off >>= 1) v = fmaxf(v, __shfl_xor(v, off));
  return v;
}

__device__ __forceinline__ unsigned short f2bf(float f) {
  union { float f; unsigned int u; } c;
  c.f = f;
  const unsigned int u = c.u;
  return (unsigned short)((u + 0x7FFFu + ((u >> 16) & 1u)) >> 16);  // RNE
}
__device__ __forceinline__ float bf2f(unsigned short h) {
  union { unsigned int u; float f; } c;
  c.u = ((unsigned int)h) << 16;
  return c.f;
}

// fused: bf16 copy + row sum-of-squares for audio++video. one wave per row.
__global__ __launch_bounds__(256) void convert_av(const float* __restrict__ A,
                                                  const float* __restrict__ V,
                                                  unsigned short* __restrict__ Xb,
                                                  float* __restrict__ sq) {
  const int row = (int)((blockIdx.x * blockDim.x + threadIdx.x) >> 6);
  const int lane = threadIdx.x & 63;
  const float* src = (row < NROWS) ? (A + (size_t)row * DIM) : (V + (size_t)(row - NROWS) * DIM);
  const float4 x = *reinterpret_cast<const float4*>(src + (lane << 2));
  float s = x.x * x.x + x.y * x.y + x.z * x.z + x.w * x.w;
  ushort4 b;
  b.x = f2bf(x.x); b.y = f2bf(x.y); b.z = f2bf(x.z); b.w = f2bf(x.w);
  *reinterpret_cast<ushort4*>(Xb + (size_t)row * DIM + (lane << 2)) = b;
  s = wave_sum(s);
  if (lane == 0) sq[row] = s;
}

__global__ __launch_bounds__(256) void convert_e(const float* __restrict__ X,
                                                 unsigned short* __restrict__ Xb,
                                                 float* __restrict__ sq) {
  const int row = (int)((blockIdx.x * blockDim.x + threadIdx.x) >> 6);
  const int lane = threadIdx.x & 63;
  const float4 x = *reinterpret_cast<const float4*>(X + (size_t)row * DIM + (lane << 2));
  float s = x.x * x.x + x.y * x.y + x.z * x.z + x.w * x.w;
  ushort4 b;
  b.x = f2bf(x.x); b.y = f2bf(x.y); b.z = f2bf(x.z); b.w = f2bf(x.w);
  *reinterpret_cast<ushort4*>(Xb + (size_t)row * DIM + (lane << 2)) = b;
  s = wave_sum(s);
  if (lane == 0) sq[row] = s;
}

// C[r][c] = sum_k X[r][k]*W[c][k] -> bf16. 128x128 tile, BK=64, 4 waves (2x2).
// global_load_lds staging, linear LDS [128][64] bf16, XOR swizzle ((row&7)<<4)
// applied on BOTH global-source offset and ds_read address (involution).
#define GBM 128
#define GBK 64
__global__ __launch_bounds__(256) void gemm_bf16(const unsigned short* __restrict__ X,
                                                 const unsigned short* __restrict__ W,
                                                 unsigned short* __restrict__ C) {
  __shared__ char AsB[GBM * GBK * 2];  // 16 KB
  __shared__ char BsB[GBM * GBK * 2];  // 16 KB
  const int tid = threadIdx.x;
  const int l = tid & 63;
  const int w = tid >> 6;
  const int wr = w >> 1, wc = w & 1;
  const int row0 = blockIdx.y * GBM;
  const int col0 = blockIdx.x * GBM;
  f32x4 acc[4][4] = {};
  for (int k0 = 0; k0 < DIM; k0 += GBK) {
#pragma unroll
    for (int j = 0; j < 4; ++j) {
      const int sbase = __builtin_amdgcn_readfirstlane((w * 4 + j) * 1024);
      const int s = sbase + (l << 4);
      const int row = s >> 7;          // 0..127
      const int colb = s & 127;        // byte within 128B row
      const int scolb = colb ^ ((row & 7) << 4);
      const char* srcA =
          (const char*)(X + (size_t)(row0 + row) * DIM + k0) + scolb;
      const char* srcB =
          (const char*)(W + (size_t)(col0 + row) * DIM + k0) + scolb;
      __builtin_amdgcn_global_load_lds(
          (const __attribute__((address_space(1))) unsigned int*)srcA,
          (__attribute__((address_space(3))) unsigned int*)(AsB + sbase), 16, 0, 0);
      __builtin_amdgcn_global_load_lds(
          (const __attribute__((address_space(1))) unsigned int*)srcB,
          (__attribute__((address_space(3))) unsigned int*)(BsB + sbase), 16, 0, 0);
    }
    __syncthreads();
#pragma unroll
    for (int ks = 0; ks < 2; ++ks) {
      short8 af[4], bq[4];
      const int cb = ks * 64 + (l >> 4) * 16;  // col byte offset
#pragma unroll
      for (int m = 0; m < 4; ++m) {
        const int ar = wr * 64 + m * 16 + (l & 15);
        af[m] = *reinterpret_cast<const short8*>(AsB + ar * 128 + (cb ^ ((ar & 7) << 4)));
      }
#pragma unroll
      for (int n = 0; n < 4; ++n) {
        const int br = wc * 64 + n * 16 + (l & 15);
        bq[n] = *reinterpret_cast<const short8*>(BsB + br * 128 + (cb ^ ((br & 7) << 4)));
      }
#pragma unroll
      for (int m = 0; m < 4; ++m)
#pragma unroll
        for (int n = 0; n < 4; ++n)
          acc[m][n] = __builtin_amdgcn_mfma_f32_16x16x32_bf16(af[m], bq[n], acc[m][n], 0, 0, 0);
    }
    __syncthreads();
  }
  // C/D layout: col = lane&15, row = (lane>>4)*4 + reg
  const int lr = (l >> 4) << 2, lc = l & 15;
#pragma unroll
  for (int m = 0; m < 4; ++m)
#pragma unroll
    for (int n = 0; n < 4; ++n) {
      unsigned short* cp =
          C + (size_t)(row0 + wr * 64 + m * 16 + lr) * MC + col0 + wc * 64 + n * 16 + lc;
#pragma unroll
      for (int r = 0; r < 4; ++r) cp[(size_t)r * MC] = f2bf(acc[m][n][r]);
    }
}

// per-row over concat rows: dist = esq + xsq - 2*dot; argmin (first index on ties);
// H = lse - sum(p*s) - M*1e-5 (analytic -sum p*log(p+1e-5), p >> 1e-5); adj = 1-H/lnM
__global__ __launch_bounds__(256) void scan_dist(const unsigned short* __restrict__ dot,
                                                 const float* __restrict__ esq,
                                                 const float* __restrict__ xsq,
                                                 int* __restrict__ idx_out,
                                                 float* __restrict__ adj_out) {
  const int row = (int)((blockIdx.x * blockDim.x + threadIdx.x) >> 6);
  const int lane = threadIdx.x & 63;
  const unsigned short* drow = dot + (size_t)row * MC;
  const float xs = xsq[row];
  float sv[16];
  float bestv = INFINITY;
  int besti = MC;
  float smax = -INFINITY;
#pragma unroll
  for (int q = 0; q < 2; ++q) {
    const int m0 = q * 512 + (lane << 3);
    const short8 d8 = *reinterpret_cast<const short8*>(drow + m0);
    const float4 e4a = *reinterpret_cast<const float4*>(esq + m0);
    const float4 e4b = *reinterpret_cast<const float4*>(esq + m0 + 4);
    const float ev[8] = {e4a.x, e4a.y, e4a.z, e4a.w, e4b.x, e4b.y, e4b.z, e4b.w};
#pragma unroll
    for (int c = 0; c < 8; ++c) {
      const float dv = ev[c] + xs - 2.0f * bf2f((unsigned short)d8[c]);
      if (dv < bestv) { bestv = dv; besti = m0 + c; }
      const float s = -sqrtf(fmaxf(dv, 0.0f));
      sv[(q << 3) + c] = s;
      smax = fmaxf(smax, s);
    }
  }
#pragma unroll
  for (int off = 32; off > 0; off >>= 1) {
    const float ov = __shfl_xor(bestv, off);
    const int oi = __shfl_xor(besti, off);
    if (ov < bestv || (ov == bestv && oi < besti)) { bestv = ov; besti = oi; }
    smax = fmaxf(smax, __shfl_xor(smax, off));
  }
  float se = 0.f, wsum = 0.f;
#pragma unroll
  for (int j = 0; j < 16; ++j) {
    const float e = expf(sv[j] - smax);
    se += e;
    wsum += e * sv[j];
  }
  se = wave_sum(se);
  wsum = wave_sum(wsum);
  if (lane == 0) {
    const float H = smax + logf(se) - wsum / se - 1e-5f * (float)MC;
    idx_out[row] = besti;
    adj_out[row] = 1.0f - H / kMaxEnt;
  }
}

// EMA scatter from bf16 copies: one block per original row pair
__global__ __launch_bounds__(256) void scatter_ema(const unsigned short* __restrict__ av,
                                                   const int* __restrict__ idx,
                                                   const float* __restrict__ adj,
                                                   float* __restrict__ acc_a,
                                                   float* __restrict__ acc_v,
                                                   float* __restrict__ cnt_a,
                                                   float* __restrict__ cnt_v) {
  const int row = blockIdx.x;
  const int d = threadIdx.x;
  const float s = bf2f(av[(size_t)row * DIM + d]) + bf2f(av[(size_t)(row + NROWS) * DIM + d]);
  const int ia = idx[row], iv = idx[row + NROWS];
  const float wa = adj[row], wv = adj[row + NROWS];
  atomicAdd(acc_a + (size_t)ia * DIM + d, wa * s);
  atomicAdd(acc_v + (size_t)iv * DIM + d, wv * s);
  if (d == 0) {
    atomicAdd(cnt_a + ia, wa);
    atomicAdd(cnt_v + iv, wv);
  }
}

// two-pass EMA count update with Laplace smoothing; single block of 1024
__global__ __launch_bounds__(1024) void ec_kernel(const float* __restrict__ ema_count,
                                                  const float* __restrict__ cnt_v,
                                                  const float* __restrict__ cnt_a,
                                                  float* __restrict__ ec_out) {
  __shared__ float red[1024];
  const int m = threadIdx.x;
  float ec = kDecay * ema_count[m] + (1.f - kDecay) * cnt_v[m];
  red[m] = ec;
  __syncthreads();
  for (int s = 512; s > 0; s >>= 1) {
    if (m < s) red[m] += red[m + s];
    __syncthreads();
  }
  float n = red[0];
  __syncthreads();
  ec = (ec + kEps) / (n + MC * kEps) * n;
  ec = kDecay * ec + (1.f - kDecay) * cnt_a[m];
  red[m] = ec;
  __syncthreads();
  for (int s = 512; s > 0; s >>= 1) {
    if (m < s) red[m] += red[m + s];
    __syncthreads();
  }
  n = red[0];
  ec = (ec + kEps) / (n + MC * kEps) * n;
  ec_out[m] = ec;
}

// emb_new = ew2/ec; en = row-normalized, emitted as bf16. one block per code
__global__ __launch_bounds__(256) void en_kernel(const float* __restrict__ ema_weight,
                                                 const float* __restrict__ acc_v,
                                                 const float* __restrict__ acc_a,
                                                 const float* __restrict__ ec,
                                                 unsigned short* __restrict__ en_b) {
  const int mcode = blockIdx.x;
  const int d = threadIdx.x;
  const size_t o = (size_t)mcode * DIM + d;
  float ew = kDecay * ema_weight[o] + 0.5f * (1.f - kDecay) * acc_v[o];
  ew = kDecay * ew + 0.5f * (1.f - kDecay) * acc_a[o];
  const float e = ew / ec[mcode];
  __shared__ float red[256];
  red[d] = e * e;
  __syncthreads();
  for (int s = 128; s > 0; s >>= 1) {
    if (d < s) red[d] += red[d + s];
    __syncthreads();
  }
  const float nrm = sqrtf(red[0]);
  en_b[o] = f2bf(e / fmaxf(nrm, 1e-8f));
}

// per-row lse of dot*inv over concat rows; coupled idx = idx[row ^ NROWS].
// per-block partials: part[b]=self, part[8192+b]=coupled
__global__ __launch_bounds__(256) void scan_nce(const unsigned short* __restrict__ dot,
                                                const float* __restrict__ xsq,
                                                const int* __restrict__ idx,
                                                float* __restrict__ part) {
  __shared__ float sp[8];
  const int row = (int)((blockIdx.x * blockDim.x + threadIdx.x) >> 6);
  const int lane = threadIdx.x & 63;
  const int wib = threadIdx.x >> 6;
  const unsigned short* drow = dot + (size_t)row * MC;
  const float inv = 1.0f / (fmaxf(sqrtf(xsq[row]), 1e-8f) * kTemp);
  float l[16];
  float lmax = -INFINITY;
#pragma unroll
  for (int q = 0; q < 2; ++q) {
    const short8 d8 = *reinterpret_cast<const short8*>(drow + q * 512 + (lane << 3));
#pragma unroll
    for (int c = 0; c < 8; ++c) {
      l[(q << 3) + c] = bf2f((unsigned short)d8[c]) * inv;
      lmax = fmaxf(lmax, l[(q << 3) + c]);
    }
  }
  lmax = wave_max(lmax);
  float se = 0.f;
#pragma unroll
  for (int j = 0; j < 16; ++j) se += expf(l[j] - lmax);
  se = wave_sum(se);
  if (lane == 0) {
    const float lse = lmax + logf(se);
    sp[wib] = bf2f(drow[idx[row]]) * inv - lse;
    sp[4 + wib] = bf2f(drow[idx[row ^ NROWS]]) * inv - lse;
  }
  __syncthreads();
  if (threadIdx.x == 0) {
    part[blockIdx.x] = sp[0] + sp[1] + sp[2] + sp[3];
    part[8192 + blockIdx.x] = sp[4] + sp[5] + sp[6] + sp[7];
  }
}

// reduce 2x8192 partials -> scalar loss. 1 block x 1024.
__global__ __launch_bounds__(1024) void finalize(const float* __restrict__ part,
                                                 float* __restrict__ out) {
  const int tid = threadIdx.x;
  const int lane = tid & 63;
  const int wid = tid >> 6;
  float ss = 0.f, sc = 0.f;
  for (int i = tid; i < 8192; i += 1024) {
    ss += part[i];
    sc += part[8192 + i];
  }
  ss = wave_sum(ss);
  sc = wave_sum(sc);
  __shared__ float red[16][2];
  if (lane == 0) { red[wid][0] = ss; red[wid][1] = sc; }
  __syncthreads();
  if (tid == 0) {
    float t0 = 0.f, t1 = 0.f;
#pragma unroll
    for (int i = 0; i < 16; ++i) { t0 += red[i][0]; t1 += red[i][1]; }
    // loss = -(C/(B*N)) * (C*S_self + (1-C)*S_coup)
    out[0] = -(kCommit / (32.0f * (float)NROWS)) * (kCommit * t0 + (1.f - kCommit) * t1);
  }
}

extern "C" void kernel_launch(void* const* d_in, const int* in_sizes, int n_in, void* d_out,
                              int out_size, void* d_ws, size_t ws_size, hipStream_t stream) {
  const float* audio = (const float*)d_in[0];
  const float* video = (const float*)d_in[1];
  const float* emb = (const float*)d_in[2];
  const float* ema_count = (const float*)d_in[3];
  const float* ema_weight = (const float*)d_in[4];
  float* out = (float*)d_out;

  float* ws = (float*)d_ws;
  unsigned short* dotbuf = (unsigned short*)ws;            // 32768*1024 bf16 = 64 MB
  size_t off = (size_t)NR2 * MC / 2;                       // in floats
  float* esq = ws + off; off += MC;
  float* xsq = ws + off; off += NR2;
  float* adj = ws + off; off += NR2;
  int* idx = (int*)(ws + off); off += NR2;
  float* cnt_a = ws + off; off += MC;
  float* cnt_v = ws + off; off += MC;
  float* acc_a = ws + off; off += (size_t)MC * DIM;
  float* acc_v = ws + off; off += (size_t)MC * DIM;
  float* ec = ws + off; off += MC;
  float* part = ws + off; off += 16384;
  unsigned short* av_bf = (unsigned short*)(ws + off); off += (size_t)NR2 * DIM / 2;
  unsigned short* e_bf = (unsigned short*)(ws + off); off += (size_t)MC * DIM / 2;
  unsigned short* en_bf = (unsigned short*)(ws + off); off += (size_t)MC * DIM / 2;

  hipMemsetAsync(cnt_a, 0, (size_t)(2 * MC + 2 * (size_t)MC * DIM) * sizeof(float), stream);

  const dim3 b256(256);
  const dim3 ggrid(MC / GBM, NR2 / GBM);  // (8, 256)

  convert_av<<<NR2 / 4, b256, 0, stream>>>(audio, video, av_bf, xsq);
  convert_e<<<MC / 4, b256, 0, stream>>>(emb, e_bf, esq);

  gemm_bf16<<<ggrid, b256, 0, stream>>>(av_bf, e_bf, dotbuf);
  scan_dist<<<NR2 / 4, b256, 0, stream>>>(dotbuf, esq, xsq, idx, adj);

  scatter_ema<<<NROWS, b256, 0, stream>>>(av_bf, idx, adj, acc_a, acc_v, cnt_a, cnt_v);
  ec_kernel<<<1, 1024, 0, stream>>>(ema_count, cnt_v, cnt_a, ec);
  en_kernel<<<MC, b256, 0, stream>>>(ema_weight, acc_v, acc_a, ec, en_bf);

  gemm_bf16<<<ggrid, b256, 0, stream>>>(av_bf, en_bf, dotbuf);
  scan_nce<<<NR2 / 4, b256, 0, stream>>>(dotbuf, xsq, idx, part);

  finalize<<<1, 1024, 0, stream>>>(part, out);
}